// Round 1
// baseline (2860.049 us; speedup 1.0000x reference)
//
#include <hip/hip_runtime.h>

#define N_NODES 100000
#define N_EDGES 1600000
#define D 128
#define TILE_M 64

// ---------------------------------------------------------------------------
// Kernel 0: transpose W [j][k] -> Wt [k][j] so GEMM B-reads are coalesced.
__global__ void k_transpose_w(const float* __restrict__ W, float* __restrict__ Wt) {
    int idx = blockIdx.x * blockDim.x + threadIdx.x;   // 0..16383
    int j = idx >> 7;
    int k = idx & 127;
    Wt[k * D + j] = W[j * D + k];
}

// ---------------------------------------------------------------------------
// Kernel 1: HW = H @ W^T  (M=100000, N=K=128).
// 64-row tile staged in LDS (row-major, stride 132 to break bank conflicts),
// Wt read from global (64 KB, L2-resident). 4x8 register blocking per thread.
__global__ __launch_bounds__(256) void k_gemm(const float* __restrict__ H,
                                              const float* __restrict__ Wt,
                                              float* __restrict__ HW) {
    __shared__ float As[TILE_M * 132];   // ~33.8 KB -> 4 blocks/CU
    const int t = threadIdx.x;
    const int rowbase = blockIdx.x * TILE_M;

    // Stage 64x128 H tile: 2048 float4 loads, 8 per thread, coalesced.
    #pragma unroll
    for (int it = 0; it < 8; ++it) {
        int f   = t + it * 256;
        int row = f >> 5;         // 0..63
        int k4  = f & 31;         // float4 index within row
        int gr  = rowbase + row;
        float4 h = (gr < N_NODES) ? ((const float4*)H)[gr * 32 + k4]
                                  : make_float4(0.f, 0.f, 0.f, 0.f);
        *(float4*)&As[row * 132 + k4 * 4] = h;
    }
    __syncthreads();

    const int tx = t & 15, ty = t >> 4;
    const int i0 = ty * 4;        // 4 rows per thread
    const int j0 = tx * 8;        // 8 cols per thread

    float acc[4][8];
    #pragma unroll
    for (int r = 0; r < 4; ++r)
        #pragma unroll
        for (int c = 0; c < 8; ++c) acc[r][c] = 0.f;

    #pragma unroll 2
    for (int k = 0; k < D; k += 4) {
        float4 a[4];
        #pragma unroll
        for (int r = 0; r < 4; ++r)
            a[r] = *(const float4*)&As[(i0 + r) * 132 + k];
        #pragma unroll
        for (int kk = 0; kk < 4; ++kk) {
            float4 b0 = *(const float4*)&Wt[(k + kk) * D + j0];
            float4 b1 = *(const float4*)&Wt[(k + kk) * D + j0 + 4];
            float bv[8] = {b0.x, b0.y, b0.z, b0.w, b1.x, b1.y, b1.z, b1.w};
            #pragma unroll
            for (int r = 0; r < 4; ++r) {
                float av = (kk == 0) ? a[r].x : (kk == 1) ? a[r].y
                         : (kk == 2) ? a[r].z : a[r].w;
                #pragma unroll
                for (int c = 0; c < 8; ++c)
                    acc[r][c] = fmaf(av, bv[c], acc[r][c]);
            }
        }
    }

    #pragma unroll
    for (int r = 0; r < 4; ++r) {
        int gr = rowbase + i0 + r;
        if (gr < N_NODES) {
            float4 o0 = make_float4(acc[r][0], acc[r][1], acc[r][2], acc[r][3]);
            float4 o1 = make_float4(acc[r][4], acc[r][5], acc[r][6], acc[r][7]);
            ((float4*)HW)[gr * 32 + (j0 >> 2)]     = o0;
            ((float4*)HW)[gr * 32 + (j0 >> 2) + 1] = o1;
        }
    }
}

// ---------------------------------------------------------------------------
// Kernel 2: edge scatter: out[rows[e], :] += vals[e] * HW[cols[e], :]
// 32 lanes per edge, each lane handles one float4 (coalesced 512B gather),
// 4 scalar f32 atomics per lane into out.
__global__ __launch_bounds__(256) void k_edge_scatter(const float* __restrict__ HW,
                                                      const float* __restrict__ vals,
                                                      const int* __restrict__ rows,
                                                      const int* __restrict__ cols,
                                                      float* __restrict__ out) {
    long long gid = (long long)blockIdx.x * blockDim.x + threadIdx.x;
    int e    = (int)(gid >> 5);
    int lane = (int)(gid & 31);
    if (e >= N_EDGES) return;
    int   r = rows[e];
    int   c = cols[e];
    float v = vals[e];
    float4 h = ((const float4*)HW)[c * 32 + lane];
    float* o = out + (size_t)r * D + lane * 4;
    atomicAdd(o + 0, v * h.x);
    atomicAdd(o + 1, v * h.y);
    atomicAdd(o + 2, v * h.z);
    atomicAdd(o + 3, v * h.w);
}

// ---------------------------------------------------------------------------
// Kernel 3: in-place ReLU over out.
__global__ void k_relu(float* __restrict__ out) {
    int i = blockIdx.x * blockDim.x + threadIdx.x;
    const int n4 = N_NODES * D / 4;   // 3.2M
    if (i < n4) {
        float4* p = (float4*)out;
        float4 x = p[i];
        x.x = fmaxf(x.x, 0.f);
        x.y = fmaxf(x.y, 0.f);
        x.z = fmaxf(x.z, 0.f);
        x.w = fmaxf(x.w, 0.f);
        p[i] = x;
    }
}

// ---------------------------------------------------------------------------
extern "C" void kernel_launch(void* const* d_in, const int* in_sizes, int n_in,
                              void* d_out, int out_size, void* d_ws, size_t ws_size,
                              hipStream_t stream) {
    const float* H    = (const float*)d_in[0];
    const float* vals = (const float*)d_in[1];
    const float* W    = (const float*)d_in[2];
    const int*   rows = (const int*)d_in[3];
    const int*   cols = (const int*)d_in[4];
    float* out = (float*)d_out;

    float* Wt = (float*)d_ws;                                  // 64 KB
    float* HW = (float*)((char*)d_ws + 65536);                 // 51.2 MB

    // W transpose (tiny)
    k_transpose_w<<<64, 256, 0, stream>>>(W, Wt);

    // HW = H @ W^T
    k_gemm<<<(N_NODES + TILE_M - 1) / TILE_M, 256, 0, stream>>>(H, Wt, HW);

    // out = 0, then scatter-accumulate, then ReLU
    hipMemsetAsync(d_out, 0, (size_t)N_NODES * D * sizeof(float), stream);
    k_edge_scatter<<<(N_EDGES * 32) / 256, 256, 0, stream>>>(HW, vals, rows, cols, out);
    k_relu<<<(N_NODES * D / 4 + 255) / 256, 256, 0, stream>>>(out);
}

// Round 2
// 457.823 us; speedup vs baseline: 6.2471x; 6.2471x over previous
//
#include <hip/hip_runtime.h>

#define N_NODES 100000
#define N_EDGES 1600000
#define D 128
#define TILE_M 64

#define N_PAD 100096            // 391 * 256
#define NSCAN_BLOCKS 391

// workspace layout (bytes)
#define WT_OFF    0u
#define HW_OFF    65536u
#define DEG_OFF   51265536u     // 100096 ints
#define LOC_OFF   51665920u     // 100096 ints (local scan)
#define OFFS_OFF  52066560u     // 100097 ints
#define CUR_OFF   52467200u     // 100097 ints
#define BSUM_OFF  52867840u     // 512 ints
#define ECOL_OFF  52869888u     // 1.6M ints
#define EVAL_OFF  59269888u     // 1.6M floats
// end ~65.7 MB

// ---------------------------------------------------------------------------
__global__ void k_transpose_w(const float* __restrict__ W, float* __restrict__ Wt) {
    int idx = blockIdx.x * blockDim.x + threadIdx.x;
    int j = idx >> 7;
    int k = idx & 127;
    Wt[k * D + j] = W[j * D + k];
}

// ---------------------------------------------------------------------------
// HW = H @ W^T  (M=100000, N=K=128)
__global__ __launch_bounds__(256) void k_gemm(const float* __restrict__ H,
                                              const float* __restrict__ Wt,
                                              float* __restrict__ HW) {
    __shared__ float As[TILE_M * 132];
    const int t = threadIdx.x;
    const int rowbase = blockIdx.x * TILE_M;

    #pragma unroll
    for (int it = 0; it < 8; ++it) {
        int f   = t + it * 256;
        int row = f >> 5;
        int k4  = f & 31;
        int gr  = rowbase + row;
        float4 h = (gr < N_NODES) ? ((const float4*)H)[gr * 32 + k4]
                                  : make_float4(0.f, 0.f, 0.f, 0.f);
        *(float4*)&As[row * 132 + k4 * 4] = h;
    }
    __syncthreads();

    const int tx = t & 15, ty = t >> 4;
    const int i0 = ty * 4;
    const int j0 = tx * 8;

    float acc[4][8];
    #pragma unroll
    for (int r = 0; r < 4; ++r)
        #pragma unroll
        for (int c = 0; c < 8; ++c) acc[r][c] = 0.f;

    #pragma unroll 2
    for (int k = 0; k < D; k += 4) {
        float4 a[4];
        #pragma unroll
        for (int r = 0; r < 4; ++r)
            a[r] = *(const float4*)&As[(i0 + r) * 132 + k];
        #pragma unroll
        for (int kk = 0; kk < 4; ++kk) {
            float4 b0 = *(const float4*)&Wt[(k + kk) * D + j0];
            float4 b1 = *(const float4*)&Wt[(k + kk) * D + j0 + 4];
            float bv[8] = {b0.x, b0.y, b0.z, b0.w, b1.x, b1.y, b1.z, b1.w};
            #pragma unroll
            for (int r = 0; r < 4; ++r) {
                float av = (kk == 0) ? a[r].x : (kk == 1) ? a[r].y
                         : (kk == 2) ? a[r].z : a[r].w;
                #pragma unroll
                for (int c = 0; c < 8; ++c)
                    acc[r][c] = fmaf(av, bv[c], acc[r][c]);
            }
        }
    }

    #pragma unroll
    for (int r = 0; r < 4; ++r) {
        int gr = rowbase + i0 + r;
        if (gr < N_NODES) {
            ((float4*)HW)[gr * 32 + (j0 >> 2)]     = make_float4(acc[r][0], acc[r][1], acc[r][2], acc[r][3]);
            ((float4*)HW)[gr * 32 + (j0 >> 2) + 1] = make_float4(acc[r][4], acc[r][5], acc[r][6], acc[r][7]);
        }
    }
}

// ---------------------------------------------------------------------------
// CSR build
__global__ void k_hist(const int* __restrict__ rows, int* __restrict__ deg) {
    int e = blockIdx.x * blockDim.x + threadIdx.x;
    if (e < N_EDGES) atomicAdd(&deg[rows[e]], 1);
}

__global__ __launch_bounds__(256) void k_scan_local(const int* __restrict__ deg,
                                                    int* __restrict__ local,
                                                    int* __restrict__ bsum) {
    __shared__ int s[256];
    int i = blockIdx.x * 256 + threadIdx.x;
    int v = deg[i];
    s[threadIdx.x] = v;
    __syncthreads();
    #pragma unroll
    for (int off = 1; off < 256; off <<= 1) {
        int t = (threadIdx.x >= off) ? s[threadIdx.x - off] : 0;
        __syncthreads();
        s[threadIdx.x] += t;
        __syncthreads();
    }
    local[i] = s[threadIdx.x] - v;            // exclusive
    if (threadIdx.x == 255) bsum[blockIdx.x] = s[255];
}

__global__ __launch_bounds__(512) void k_scan_bsums(int* __restrict__ bsum) {
    __shared__ int s[512];
    int v = (threadIdx.x < NSCAN_BLOCKS) ? bsum[threadIdx.x] : 0;
    s[threadIdx.x] = v;
    __syncthreads();
    #pragma unroll
    for (int off = 1; off < 512; off <<= 1) {
        int t = (threadIdx.x >= off) ? s[threadIdx.x - off] : 0;
        __syncthreads();
        s[threadIdx.x] += t;
        __syncthreads();
    }
    if (threadIdx.x < NSCAN_BLOCKS) bsum[threadIdx.x] = s[threadIdx.x] - v;  // exclusive
}

__global__ __launch_bounds__(256) void k_scan_add(const int* __restrict__ local,
                                                  const int* __restrict__ bsum,
                                                  int* __restrict__ offs,
                                                  int* __restrict__ cursor) {
    int i = blockIdx.x * 256 + threadIdx.x;
    int o = local[i] + bsum[blockIdx.x];
    offs[i]   = o;
    cursor[i] = o;
}

__global__ void k_bucket(const int* __restrict__ rows, const int* __restrict__ cols,
                         const float* __restrict__ vals, int* __restrict__ cursor,
                         int* __restrict__ ecol, float* __restrict__ eval) {
    int e = blockIdx.x * blockDim.x + threadIdx.x;
    if (e < N_EDGES) {
        int pos = atomicAdd(&cursor[rows[e]], 1);
        ecol[pos] = cols[e];
        eval[pos] = vals[e];
    }
}

// ---------------------------------------------------------------------------
// Gather SpMM + fused ReLU: out[n,:] = relu( sum_{j in CSR(n)} eval[j]*HW[ecol[j],:] )
// 32 lanes per node, one float4 per lane. Zero atomics.
__global__ __launch_bounds__(256) void k_spmm_gather(const float* __restrict__ HW,
                                                     const int* __restrict__ offs,
                                                     const int* __restrict__ ecol,
                                                     const float* __restrict__ eval,
                                                     float* __restrict__ out) {
    int gid  = blockIdx.x * blockDim.x + threadIdx.x;
    int node = gid >> 5;
    int lane = gid & 31;
    if (node >= N_NODES) return;
    int beg = offs[node], end = offs[node + 1];

    float4 acc = make_float4(0.f, 0.f, 0.f, 0.f);
    int j = beg;
    for (; j + 1 < end; j += 2) {
        int   c0 = ecol[j],     c1 = ecol[j + 1];
        float v0 = eval[j],     v1 = eval[j + 1];
        float4 h0 = ((const float4*)HW)[c0 * 32 + lane];
        float4 h1 = ((const float4*)HW)[c1 * 32 + lane];
        acc.x = fmaf(v0, h0.x, acc.x); acc.y = fmaf(v0, h0.y, acc.y);
        acc.z = fmaf(v0, h0.z, acc.z); acc.w = fmaf(v0, h0.w, acc.w);
        acc.x = fmaf(v1, h1.x, acc.x); acc.y = fmaf(v1, h1.y, acc.y);
        acc.z = fmaf(v1, h1.z, acc.z); acc.w = fmaf(v1, h1.w, acc.w);
    }
    if (j < end) {
        int   c = ecol[j];
        float v = eval[j];
        float4 h = ((const float4*)HW)[c * 32 + lane];
        acc.x = fmaf(v, h.x, acc.x); acc.y = fmaf(v, h.y, acc.y);
        acc.z = fmaf(v, h.z, acc.z); acc.w = fmaf(v, h.w, acc.w);
    }
    acc.x = fmaxf(acc.x, 0.f); acc.y = fmaxf(acc.y, 0.f);
    acc.z = fmaxf(acc.z, 0.f); acc.w = fmaxf(acc.w, 0.f);
    ((float4*)out)[node * 32 + lane] = acc;
}

// ---------------------------------------------------------------------------
extern "C" void kernel_launch(void* const* d_in, const int* in_sizes, int n_in,
                              void* d_out, int out_size, void* d_ws, size_t ws_size,
                              hipStream_t stream) {
    const float* H    = (const float*)d_in[0];
    const float* vals = (const float*)d_in[1];
    const float* W    = (const float*)d_in[2];
    const int*   rows = (const int*)d_in[3];
    const int*   cols = (const int*)d_in[4];
    float* out = (float*)d_out;

    char* ws = (char*)d_ws;
    float* Wt     = (float*)(ws + WT_OFF);
    float* HW     = (float*)(ws + HW_OFF);
    int*   deg    = (int*)(ws + DEG_OFF);
    int*   local  = (int*)(ws + LOC_OFF);
    int*   offs   = (int*)(ws + OFFS_OFF);
    int*   cursor = (int*)(ws + CUR_OFF);
    int*   bsum   = (int*)(ws + BSUM_OFF);
    int*   ecol   = (int*)(ws + ECOL_OFF);
    float* eval   = (float*)(ws + EVAL_OFF);

    // dense path: HW = H @ W^T
    k_transpose_w<<<64, 256, 0, stream>>>(W, Wt);
    k_gemm<<<(N_NODES + TILE_M - 1) / TILE_M, 256, 0, stream>>>(H, Wt, HW);

    // CSR build
    hipMemsetAsync(deg, 0, N_PAD * sizeof(int), stream);
    k_hist<<<(N_EDGES + 255) / 256, 256, 0, stream>>>(rows, deg);
    k_scan_local<<<NSCAN_BLOCKS, 256, 0, stream>>>(deg, local, bsum);
    k_scan_bsums<<<1, 512, 0, stream>>>(bsum);
    k_scan_add<<<NSCAN_BLOCKS, 256, 0, stream>>>(local, bsum, offs, cursor);
    k_bucket<<<(N_EDGES + 255) / 256, 256, 0, stream>>>(rows, cols, vals, cursor, ecol, eval);

    // atomic-free gather SpMM + ReLU
    k_spmm_gather<<<(N_NODES * 32 + 255) / 256, 256, 0, stream>>>(HW, offs, ecol, eval, out);
}

// Round 3
// 427.968 us; speedup vs baseline: 6.6829x; 1.0698x over previous
//
#include <hip/hip_runtime.h>

#define N_NODES 100000
#define N_EDGES 1600000
#define D 128
#define TILE_M 64

#define N_PAD 100096            // 391 * 256
#define NSCAN_BLOCKS 391

// workspace layout (bytes)
#define WT_OFF    0u            // 64 KB f32 Wt
#define HWB_OFF   65536u        // 25.6 MB bf16 HW
#define DEG_OFF   25665536u     // 100096 ints
#define LOC_OFF   26065920u     // 100096 ints
#define OFFS_OFF  26466304u     // 100097 ints (padded)
#define CUR_OFF   26866944u     // 100097 ints (padded)
#define BSUM_OFF  27267584u     // 512 ints
#define EPACK_OFF 27269632u     // 1.6M int2 = 12.8 MB
// end ~40.1 MB

typedef unsigned int uint;

__device__ __forceinline__ unsigned short f2bf(float x) {
    uint u = __float_as_uint(x);
    uint r = u + 0x7fffu + ((u >> 16) & 1u);   // round-to-nearest-even
    return (unsigned short)(r >> 16);
}

// ---------------------------------------------------------------------------
__global__ void k_transpose_w(const float* __restrict__ W, float* __restrict__ Wt) {
    int idx = blockIdx.x * blockDim.x + threadIdx.x;
    int j = idx >> 7;
    int k = idx & 127;
    Wt[k * D + j] = W[j * D + k];
}

// ---------------------------------------------------------------------------
// HWb = bf16( H @ W^T )  (M=100000, N=K=128)
__global__ __launch_bounds__(256) void k_gemm(const float* __restrict__ H,
                                              const float* __restrict__ Wt,
                                              unsigned short* __restrict__ HWb) {
    __shared__ float As[TILE_M * 132];
    const int t = threadIdx.x;
    const int rowbase = blockIdx.x * TILE_M;

    #pragma unroll
    for (int it = 0; it < 8; ++it) {
        int f   = t + it * 256;
        int row = f >> 5;
        int k4  = f & 31;
        int gr  = rowbase + row;
        float4 h = (gr < N_NODES) ? ((const float4*)H)[gr * 32 + k4]
                                  : make_float4(0.f, 0.f, 0.f, 0.f);
        *(float4*)&As[row * 132 + k4 * 4] = h;
    }
    __syncthreads();

    const int tx = t & 15, ty = t >> 4;
    const int i0 = ty * 4;
    const int j0 = tx * 8;

    float acc[4][8];
    #pragma unroll
    for (int r = 0; r < 4; ++r)
        #pragma unroll
        for (int c = 0; c < 8; ++c) acc[r][c] = 0.f;

    #pragma unroll 2
    for (int k = 0; k < D; k += 4) {
        float4 a[4];
        #pragma unroll
        for (int r = 0; r < 4; ++r)
            a[r] = *(const float4*)&As[(i0 + r) * 132 + k];
        #pragma unroll
        for (int kk = 0; kk < 4; ++kk) {
            float4 b0 = *(const float4*)&Wt[(k + kk) * D + j0];
            float4 b1 = *(const float4*)&Wt[(k + kk) * D + j0 + 4];
            float bv[8] = {b0.x, b0.y, b0.z, b0.w, b1.x, b1.y, b1.z, b1.w};
            #pragma unroll
            for (int r = 0; r < 4; ++r) {
                float av = (kk == 0) ? a[r].x : (kk == 1) ? a[r].y
                         : (kk == 2) ? a[r].z : a[r].w;
                #pragma unroll
                for (int c = 0; c < 8; ++c)
                    acc[r][c] = fmaf(av, bv[c], acc[r][c]);
            }
        }
    }

    #pragma unroll
    for (int r = 0; r < 4; ++r) {
        int gr = rowbase + i0 + r;
        if (gr < N_NODES) {
            uint4 q;
            q.x = (uint)f2bf(acc[r][0]) | ((uint)f2bf(acc[r][1]) << 16);
            q.y = (uint)f2bf(acc[r][2]) | ((uint)f2bf(acc[r][3]) << 16);
            q.z = (uint)f2bf(acc[r][4]) | ((uint)f2bf(acc[r][5]) << 16);
            q.w = (uint)f2bf(acc[r][6]) | ((uint)f2bf(acc[r][7]) << 16);
            ((uint4*)(HWb + (size_t)gr * D))[tx] = q;   // 8 bf16 = 16 B
        }
    }
}

// ---------------------------------------------------------------------------
// CSR build
__global__ void k_hist(const int* __restrict__ rows, int* __restrict__ deg) {
    int e = blockIdx.x * blockDim.x + threadIdx.x;
    if (e < N_EDGES) atomicAdd(&deg[rows[e]], 1);
}

__global__ __launch_bounds__(256) void k_scan_local(const int* __restrict__ deg,
                                                    int* __restrict__ local,
                                                    int* __restrict__ bsum) {
    __shared__ int s[256];
    int i = blockIdx.x * 256 + threadIdx.x;
    int v = deg[i];
    s[threadIdx.x] = v;
    __syncthreads();
    #pragma unroll
    for (int off = 1; off < 256; off <<= 1) {
        int t = (threadIdx.x >= off) ? s[threadIdx.x - off] : 0;
        __syncthreads();
        s[threadIdx.x] += t;
        __syncthreads();
    }
    local[i] = s[threadIdx.x] - v;            // exclusive
    if (threadIdx.x == 255) bsum[blockIdx.x] = s[255];
}

__global__ __launch_bounds__(512) void k_scan_bsums(int* __restrict__ bsum) {
    __shared__ int s[512];
    int v = (threadIdx.x < NSCAN_BLOCKS) ? bsum[threadIdx.x] : 0;
    s[threadIdx.x] = v;
    __syncthreads();
    #pragma unroll
    for (int off = 1; off < 512; off <<= 1) {
        int t = (threadIdx.x >= off) ? s[threadIdx.x - off] : 0;
        __syncthreads();
        s[threadIdx.x] += t;
        __syncthreads();
    }
    if (threadIdx.x < NSCAN_BLOCKS) bsum[threadIdx.x] = s[threadIdx.x] - v;  // exclusive
}

__global__ __launch_bounds__(256) void k_scan_add(const int* __restrict__ local,
                                                  const int* __restrict__ bsum,
                                                  int* __restrict__ offs,
                                                  int* __restrict__ cursor) {
    int i = blockIdx.x * 256 + threadIdx.x;
    int o = local[i] + bsum[blockIdx.x];
    offs[i]   = o;
    cursor[i] = o;
}

// Pack (col, val) into one 8 B store -> 1 dirty cacheline per edge, not 2.
__global__ void k_bucket(const int* __restrict__ rows, const int* __restrict__ cols,
                         const float* __restrict__ vals, int* __restrict__ cursor,
                         int2* __restrict__ epack) {
    int e = blockIdx.x * blockDim.x + threadIdx.x;
    if (e < N_EDGES) {
        int pos = atomicAdd(&cursor[rows[e]], 1);
        epack[pos] = make_int2(cols[e], __float_as_int(vals[e]));
    }
}

// ---------------------------------------------------------------------------
// Gather SpMM + fused ReLU over bf16 HW rows (256 B each).
// 16 lanes per node; lane reads uint4 = 8 bf16, accumulates fp32.
__global__ __launch_bounds__(256) void k_spmm_gather(const unsigned short* __restrict__ HWb,
                                                     const int* __restrict__ offs,
                                                     const int2* __restrict__ epack,
                                                     float* __restrict__ out) {
    int gid  = blockIdx.x * blockDim.x + threadIdx.x;
    int node = gid >> 4;
    int lane = gid & 15;
    if (node >= N_NODES) return;
    int beg = offs[node], end = offs[node + 1];

    float acc[8];
    #pragma unroll
    for (int c = 0; c < 8; ++c) acc[c] = 0.f;

    for (int j = beg; j < end; ++j) {
        int2  e = epack[j];                       // broadcast across the 16 lanes
        float v = __int_as_float(e.y);
        uint4 q = ((const uint4*)(HWb + (size_t)e.x * D))[lane];
        acc[0] = fmaf(v, __uint_as_float(q.x << 16),         acc[0]);
        acc[1] = fmaf(v, __uint_as_float(q.x & 0xffff0000u), acc[1]);
        acc[2] = fmaf(v, __uint_as_float(q.y << 16),         acc[2]);
        acc[3] = fmaf(v, __uint_as_float(q.y & 0xffff0000u), acc[3]);
        acc[4] = fmaf(v, __uint_as_float(q.z << 16),         acc[4]);
        acc[5] = fmaf(v, __uint_as_float(q.z & 0xffff0000u), acc[5]);
        acc[6] = fmaf(v, __uint_as_float(q.w << 16),         acc[6]);
        acc[7] = fmaf(v, __uint_as_float(q.w & 0xffff0000u), acc[7]);
    }

    float4 o0 = make_float4(fmaxf(acc[0], 0.f), fmaxf(acc[1], 0.f),
                            fmaxf(acc[2], 0.f), fmaxf(acc[3], 0.f));
    float4 o1 = make_float4(fmaxf(acc[4], 0.f), fmaxf(acc[5], 0.f),
                            fmaxf(acc[6], 0.f), fmaxf(acc[7], 0.f));
    ((float4*)out)[node * 32 + lane * 2]     = o0;
    ((float4*)out)[node * 32 + lane * 2 + 1] = o1;
}

// ---------------------------------------------------------------------------
extern "C" void kernel_launch(void* const* d_in, const int* in_sizes, int n_in,
                              void* d_out, int out_size, void* d_ws, size_t ws_size,
                              hipStream_t stream) {
    const float* H    = (const float*)d_in[0];
    const float* vals = (const float*)d_in[1];
    const float* W    = (const float*)d_in[2];
    const int*   rows = (const int*)d_in[3];
    const int*   cols = (const int*)d_in[4];
    float* out = (float*)d_out;

    char* ws = (char*)d_ws;
    float*          Wt     = (float*)(ws + WT_OFF);
    unsigned short* HWb    = (unsigned short*)(ws + HWB_OFF);
    int*            deg    = (int*)(ws + DEG_OFF);
    int*            local  = (int*)(ws + LOC_OFF);
    int*            offs   = (int*)(ws + OFFS_OFF);
    int*            cursor = (int*)(ws + CUR_OFF);
    int*            bsum   = (int*)(ws + BSUM_OFF);
    int2*           epack  = (int2*)(ws + EPACK_OFF);

    // dense path: HWb = bf16(H @ W^T)
    k_transpose_w<<<64, 256, 0, stream>>>(W, Wt);
    k_gemm<<<(N_NODES + TILE_M - 1) / TILE_M, 256, 0, stream>>>(H, Wt, HWb);

    // CSR build
    hipMemsetAsync(deg, 0, N_PAD * sizeof(int), stream);
    k_hist<<<(N_EDGES + 255) / 256, 256, 0, stream>>>(rows, deg);
    k_scan_local<<<NSCAN_BLOCKS, 256, 0, stream>>>(deg, local, bsum);
    k_scan_bsums<<<1, 512, 0, stream>>>(bsum);
    k_scan_add<<<NSCAN_BLOCKS, 256, 0, stream>>>(local, bsum, offs, cursor);
    k_bucket<<<(N_EDGES + 255) / 256, 256, 0, stream>>>(rows, cols, vals, cursor, epack);

    // atomic-free gather SpMM + ReLU
    k_spmm_gather<<<(N_NODES * 16 + 255) / 256, 256, 0, stream>>>(HWb, offs, epack, out);
}

// Round 4
// 375.951 us; speedup vs baseline: 7.6075x; 1.1384x over previous
//
#include <hip/hip_runtime.h>

#define N_NODES 100000
#define N_EDGES 1600000
#define D 128

#define N_PAD 100096            // 391 * 256
#define NSCAN_BLOCKS 391

#define NPART 8                 // one row-range per XCD
#define ROWS_PER_PART 12500     // 100000 / 8
#define NCHUNK 512
#define EDGES_PER_CHUNK 3125    // 1600000 / 512

// workspace layout (bytes)
#define WB_OFF    0u            // 32 KB bf16 Wb
#define HWB_OFF   65536u        // 25.6 MB bf16 HW
#define DEG_OFF   25665536u     // 100096 ints
#define LOC_OFF   26065920u     // 100096 ints
#define OFFS_OFF  26466304u     // 100097 ints (padded)
#define CUR_OFF   26866944u     // 100097 ints (padded)
#define BSUM_OFF  27267584u     // 512 ints
#define EPACK_OFF 27269632u     // 1.6M int2 = 12.8 MB
// end ~40.1 MB

typedef unsigned int uint;
typedef __attribute__((ext_vector_type(4))) float f32x4;
typedef __attribute__((ext_vector_type(8))) short bf16x8;

__device__ __forceinline__ unsigned short f2bf(float x) {
    uint u = __float_as_uint(x);
    uint r = u + 0x7fffu + ((u >> 16) & 1u);   // round-to-nearest-even
    return (unsigned short)(r >> 16);
}

// ---------------------------------------------------------------------------
// Wb = bf16(W), row-major [n][k] — B-frag reads W rows directly (no transpose:
// B[k][n] = W[n][k], and the B fragment wants 8 consecutive k of a fixed n).
__global__ void k_cast_w(const float* __restrict__ W, unsigned short* __restrict__ Wb) {
    int i = blockIdx.x * blockDim.x + threadIdx.x;   // 0..16383
    Wb[i] = f2bf(W[i]);
}

// ---------------------------------------------------------------------------
// HWb = bf16( H @ W^T ) via mfma_f32_16x16x32_bf16. One wave per 16 rows.
// A-frag: A[m=lane&15][k=quad*8+j] = 8 contiguous H-row floats, cast in-reg.
// B-frag: B[k=quad*8+j][n=lane&15] = 8 contiguous bf16 of Wb row n.
// C/D:    col=lane&15, row=quad*4+reg   [verified m89 layout]
__global__ __launch_bounds__(256) void k_gemm_mfma(const float* __restrict__ H,
                                                   const unsigned short* __restrict__ Wb,
                                                   unsigned short* __restrict__ HWb) {
    const int wave = threadIdx.x >> 6;
    const int lane = threadIdx.x & 63;
    const int rowtile = blockIdx.x * 4 + wave;       // 0..6249
    if (rowtile >= N_NODES / 16) return;
    const int rowbase = rowtile * 16;
    const int m    = lane & 15;
    const int quad = lane >> 4;

    f32x4 acc[8];
    #pragma unroll
    for (int nt = 0; nt < 8; ++nt) acc[nt] = (f32x4){0.f, 0.f, 0.f, 0.f};

    const float* hrow = H + (size_t)(rowbase + m) * D;

    #pragma unroll
    for (int ks = 0; ks < 4; ++ks) {
        const int k0 = ks * 32 + quad * 8;
        float4 a0 = *(const float4*)(hrow + k0);
        float4 a1 = *(const float4*)(hrow + k0 + 4);
        bf16x8 afr;
        afr[0] = (short)f2bf(a0.x); afr[1] = (short)f2bf(a0.y);
        afr[2] = (short)f2bf(a0.z); afr[3] = (short)f2bf(a0.w);
        afr[4] = (short)f2bf(a1.x); afr[5] = (short)f2bf(a1.y);
        afr[6] = (short)f2bf(a1.z); afr[7] = (short)f2bf(a1.w);
        #pragma unroll
        for (int nt = 0; nt < 8; ++nt) {
            bf16x8 bfr = *(const bf16x8*)(Wb + (size_t)(nt * 16 + m) * D + k0);
            acc[nt] = __builtin_amdgcn_mfma_f32_16x16x32_bf16(afr, bfr, acc[nt], 0, 0, 0);
        }
    }

    #pragma unroll
    for (int nt = 0; nt < 8; ++nt) {
        #pragma unroll
        for (int r = 0; r < 4; ++r) {
            int orow = rowbase + quad * 4 + r;
            HWb[(size_t)orow * D + nt * 16 + m] = f2bf(acc[nt][r]);
        }
    }
}

// ---------------------------------------------------------------------------
// CSR build
__global__ void k_hist(const int* __restrict__ rows, int* __restrict__ deg) {
    int e = blockIdx.x * blockDim.x + threadIdx.x;
    if (e < N_EDGES) atomicAdd(&deg[rows[e]], 1);
}

__global__ __launch_bounds__(256) void k_scan_local(const int* __restrict__ deg,
                                                    int* __restrict__ local,
                                                    int* __restrict__ bsum) {
    __shared__ int s[256];
    int i = blockIdx.x * 256 + threadIdx.x;
    int v = deg[i];
    s[threadIdx.x] = v;
    __syncthreads();
    #pragma unroll
    for (int off = 1; off < 256; off <<= 1) {
        int t = (threadIdx.x >= off) ? s[threadIdx.x - off] : 0;
        __syncthreads();
        s[threadIdx.x] += t;
        __syncthreads();
    }
    local[i] = s[threadIdx.x] - v;            // exclusive
    if (threadIdx.x == 255) bsum[blockIdx.x] = s[255];
}

__global__ __launch_bounds__(512) void k_scan_bsums(int* __restrict__ bsum) {
    __shared__ int s[512];
    int v = (threadIdx.x < NSCAN_BLOCKS) ? bsum[threadIdx.x] : 0;
    s[threadIdx.x] = v;
    __syncthreads();
    #pragma unroll
    for (int off = 1; off < 512; off <<= 1) {
        int t = (threadIdx.x >= off) ? s[threadIdx.x - off] : 0;
        __syncthreads();
        s[threadIdx.x] += t;
        __syncthreads();
    }
    if (threadIdx.x < NSCAN_BLOCKS) bsum[threadIdx.x] = s[threadIdx.x] - v;  // exclusive
}

__global__ __launch_bounds__(256) void k_scan_add(const int* __restrict__ local,
                                                  const int* __restrict__ bsum,
                                                  int* __restrict__ offs,
                                                  int* __restrict__ cursor) {
    int i = blockIdx.x * 256 + threadIdx.x;
    int o = local[i] + bsum[blockIdx.x];
    offs[i]   = o;
    cursor[i] = o;
}

// ---------------------------------------------------------------------------
// XCD-partitioned bucket: block (blockIdx & 7) handles one 12500-row range so
// each XCD's epack write window is ~1.6 MB (< 4 MB L2) -> full-line
// write-combining instead of 1 partial-line eviction per edge.
__global__ __launch_bounds__(256) void k_bucket_part(const int* __restrict__ rows,
                                                     const int* __restrict__ cols,
                                                     const float* __restrict__ vals,
                                                     int* __restrict__ cursor,
                                                     int2* __restrict__ epack) {
    const int part  = blockIdx.x & (NPART - 1);
    const int chunk = blockIdx.x >> 3;
    const int row_lo = part * ROWS_PER_PART;
    const int row_hi = row_lo + ROWS_PER_PART;
    const int e0 = chunk * EDGES_PER_CHUNK;
    const int e1 = e0 + EDGES_PER_CHUNK;
    for (int e = e0 + threadIdx.x; e < e1; e += 256) {
        int r = rows[e];
        if (r >= row_lo && r < row_hi) {
            int pos = atomicAdd(&cursor[r], 1);
            epack[pos] = make_int2(cols[e], __float_as_int(vals[e]));
        }
    }
}

// ---------------------------------------------------------------------------
// Gather SpMM + fused ReLU over bf16 HW rows (256 B each).
__global__ __launch_bounds__(256) void k_spmm_gather(const unsigned short* __restrict__ HWb,
                                                     const int* __restrict__ offs,
                                                     const int2* __restrict__ epack,
                                                     float* __restrict__ out) {
    int gid  = blockIdx.x * blockDim.x + threadIdx.x;
    int node = gid >> 4;
    int lane = gid & 15;
    if (node >= N_NODES) return;
    int beg = offs[node], end = offs[node + 1];

    float acc[8];
    #pragma unroll
    for (int c = 0; c < 8; ++c) acc[c] = 0.f;

    for (int j = beg; j < end; ++j) {
        int2  e = epack[j];
        float v = __int_as_float(e.y);
        uint4 q = ((const uint4*)(HWb + (size_t)e.x * D))[lane];
        acc[0] = fmaf(v, __uint_as_float(q.x << 16),         acc[0]);
        acc[1] = fmaf(v, __uint_as_float(q.x & 0xffff0000u), acc[1]);
        acc[2] = fmaf(v, __uint_as_float(q.y << 16),         acc[2]);
        acc[3] = fmaf(v, __uint_as_float(q.y & 0xffff0000u), acc[3]);
        acc[4] = fmaf(v, __uint_as_float(q.z << 16),         acc[4]);
        acc[5] = fmaf(v, __uint_as_float(q.z & 0xffff0000u), acc[5]);
        acc[6] = fmaf(v, __uint_as_float(q.w << 16),         acc[6]);
        acc[7] = fmaf(v, __uint_as_float(q.w & 0xffff0000u), acc[7]);
    }

    float4 o0 = make_float4(fmaxf(acc[0], 0.f), fmaxf(acc[1], 0.f),
                            fmaxf(acc[2], 0.f), fmaxf(acc[3], 0.f));
    float4 o1 = make_float4(fmaxf(acc[4], 0.f), fmaxf(acc[5], 0.f),
                            fmaxf(acc[6], 0.f), fmaxf(acc[7], 0.f));
    ((float4*)out)[node * 32 + lane * 2]     = o0;
    ((float4*)out)[node * 32 + lane * 2 + 1] = o1;
}

// ---------------------------------------------------------------------------
extern "C" void kernel_launch(void* const* d_in, const int* in_sizes, int n_in,
                              void* d_out, int out_size, void* d_ws, size_t ws_size,
                              hipStream_t stream) {
    const float* H    = (const float*)d_in[0];
    const float* vals = (const float*)d_in[1];
    const float* W    = (const float*)d_in[2];
    const int*   rows = (const int*)d_in[3];
    const int*   cols = (const int*)d_in[4];
    float* out = (float*)d_out;

    char* ws = (char*)d_ws;
    unsigned short* Wb     = (unsigned short*)(ws + WB_OFF);
    unsigned short* HWb    = (unsigned short*)(ws + HWB_OFF);
    int*            deg    = (int*)(ws + DEG_OFF);
    int*            local  = (int*)(ws + LOC_OFF);
    int*            offs   = (int*)(ws + OFFS_OFF);
    int*            cursor = (int*)(ws + CUR_OFF);
    int*            bsum   = (int*)(ws + BSUM_OFF);
    int2*           epack  = (int2*)(ws + EPACK_OFF);

    // dense path: HWb = bf16(H @ W^T), MFMA
    k_cast_w<<<64, 256, 0, stream>>>(W, Wb);
    k_gemm_mfma<<<(N_NODES / 16 + 3) / 4, 256, 0, stream>>>(H, Wb, HWb);

    // CSR build
    hipMemsetAsync(deg, 0, N_PAD * sizeof(int), stream);
    k_hist<<<(N_EDGES + 255) / 256, 256, 0, stream>>>(rows, deg);
    k_scan_local<<<NSCAN_BLOCKS, 256, 0, stream>>>(deg, local, bsum);
    k_scan_bsums<<<1, 512, 0, stream>>>(bsum);
    k_scan_add<<<NSCAN_BLOCKS, 256, 0, stream>>>(local, bsum, offs, cursor);
    k_bucket_part<<<NPART * NCHUNK, 256, 0, stream>>>(rows, cols, vals, cursor, epack);

    // atomic-free gather SpMM + ReLU
    k_spmm_gather<<<(N_NODES * 16 + 255) / 256, 256, 0, stream>>>(HWb, offs, epack, out);
}

// Round 5
// 281.951 us; speedup vs baseline: 10.1438x; 1.3334x over previous
//
#include <hip/hip_runtime.h>

#define N_NODES 100000
#define N_EDGES 1600000
#define D 128

#define NB 782                  // coarse buckets: 128 rows each (781*128=99968, last partial)
#define SLOT 2560               // slots per bucket (mean 2046, sigma ~45 -> +11 sigma slack)
#define CHUNK 6400              // edges per bucket_coarse block
#define NBLK_BUCKET 250         // 250 * 6400 = 1.6M

// workspace layout (bytes)
#define WB_OFF     0u           // 32 KB bf16 W
#define HWB_OFF    65536u       // 25.6 MB bf16 HW
#define BCNT_OFF   25665536u    // 782 ints (pad to 4 KB)
#define RANGES_OFF 25669632u    // 100096 int2 = 800,768 B (pad)
#define EPACK0_OFF 26472448u    // NB*SLOT int2 = 16,015,360 B
#define EPACK1_OFF 42487808u    // NB*SLOT int2 = 16,015,360 B
// end 58,503,168 B (~58.5 MB)

typedef unsigned int uint;
typedef __attribute__((ext_vector_type(4))) float f32x4;
typedef __attribute__((ext_vector_type(8))) short bf16x8;

__device__ __forceinline__ unsigned short f2bf(float x) {
    uint u = __float_as_uint(x);
    uint r = u + 0x7fffu + ((u >> 16) & 1u);   // round-to-nearest-even
    return (unsigned short)(r >> 16);
}

// ---------------------------------------------------------------------------
__global__ void k_cast_w(const float* __restrict__ W, unsigned short* __restrict__ Wb) {
    int i = blockIdx.x * blockDim.x + threadIdx.x;   // 0..16383
    Wb[i] = f2bf(W[i]);
}

// ---------------------------------------------------------------------------
// HWb = bf16( H @ W^T ) via mfma_f32_16x16x32_bf16. One wave per 16 rows.
__global__ __launch_bounds__(256) void k_gemm_mfma(const float* __restrict__ H,
                                                   const unsigned short* __restrict__ Wb,
                                                   unsigned short* __restrict__ HWb) {
    const int wave = threadIdx.x >> 6;
    const int lane = threadIdx.x & 63;
    const int rowtile = blockIdx.x * 4 + wave;       // 0..6249
    if (rowtile >= N_NODES / 16) return;
    const int rowbase = rowtile * 16;
    const int m    = lane & 15;
    const int quad = lane >> 4;

    f32x4 acc[8];
    #pragma unroll
    for (int nt = 0; nt < 8; ++nt) acc[nt] = (f32x4){0.f, 0.f, 0.f, 0.f};

    const float* hrow = H + (size_t)(rowbase + m) * D;

    #pragma unroll
    for (int ks = 0; ks < 4; ++ks) {
        const int k0 = ks * 32 + quad * 8;
        float4 a0 = *(const float4*)(hrow + k0);
        float4 a1 = *(const float4*)(hrow + k0 + 4);
        bf16x8 afr;
        afr[0] = (short)f2bf(a0.x); afr[1] = (short)f2bf(a0.y);
        afr[2] = (short)f2bf(a0.z); afr[3] = (short)f2bf(a0.w);
        afr[4] = (short)f2bf(a1.x); afr[5] = (short)f2bf(a1.y);
        afr[6] = (short)f2bf(a1.z); afr[7] = (short)f2bf(a1.w);
        #pragma unroll
        for (int nt = 0; nt < 8; ++nt) {
            bf16x8 bfr = *(const bf16x8*)(Wb + (size_t)(nt * 16 + m) * D + k0);
            acc[nt] = __builtin_amdgcn_mfma_f32_16x16x32_bf16(afr, bfr, acc[nt], 0, 0, 0);
        }
    }

    #pragma unroll
    for (int nt = 0; nt < 8; ++nt) {
        #pragma unroll
        for (int r = 0; r < 4; ++r) {
            int orow = rowbase + quad * 4 + r;
            HWb[(size_t)orow * D + nt * 16 + m] = f2bf(acc[nt][r]);
        }
    }
}

// ---------------------------------------------------------------------------
// Pass 1: coarse-bucket edges by row>>7. Each block counts its chunk's edges
// per bucket in LDS, reserves a contiguous span per bucket with ONE global
// atomic, then places. All writes to a span come from one block and are dense
// in time -> full-line write-combining.
// epack0 entry: x = (local_row<<17) | col, y = val bits.
__global__ __launch_bounds__(256) void k_bucket_coarse(const int* __restrict__ rows,
                                                       const int* __restrict__ cols,
                                                       const float* __restrict__ vals,
                                                       int* __restrict__ bcnt,
                                                       int2* __restrict__ epack0) {
    __shared__ int srows[CHUNK];        // 25.6 KB
    __shared__ int hist[NB];            // 3.1 KB
    __shared__ int cur[NB];             // 3.1 KB
    const int tid = threadIdx.x;
    const int e0  = blockIdx.x * CHUNK;

    for (int b = tid; b < NB; b += 256) hist[b] = 0;
    __syncthreads();

    for (int i = tid; i < CHUNK; i += 256) {
        int r = rows[e0 + i];
        srows[i] = r;
        atomicAdd(&hist[r >> 7], 1);
    }
    __syncthreads();

    // reserve global span per bucket; cur = absolute slot cursor
    for (int b = tid; b < NB; b += 256) {
        int c = hist[b];
        int base = (c > 0) ? atomicAdd(&bcnt[b], c) : 0;
        cur[b] = b * SLOT + base;
    }
    __syncthreads();

    for (int i = tid; i < CHUNK; i += 256) {
        int r = srows[i];
        int b = r >> 7;
        int p = atomicAdd(&cur[b], 1);
        epack0[p] = make_int2(((r & 127) << 17) | cols[e0 + i],
                              __float_as_int(vals[e0 + i]));
    }
}

// ---------------------------------------------------------------------------
// Pass 2: one block per bucket. LDS counting sort by local row (7 bits),
// emit row-sorted epack1 (col,val) + per-row (start,end) ranges. All global
// writes dense/streaming.
__global__ __launch_bounds__(256) void k_sort_bucket(const int* __restrict__ bcnt,
                                                     const int2* __restrict__ epack0,
                                                     int2* __restrict__ epack1,
                                                     int2* __restrict__ ranges) {
    __shared__ int2 se[SLOT];           // 20.5 KB
    __shared__ int hist[128];
    __shared__ int sc[128];
    __shared__ int cur[128];
    const int tid  = threadIdx.x;
    const int b    = blockIdx.x;
    const int base = b * SLOT;
    const int n_e  = bcnt[b];

    if (tid < 128) hist[tid] = 0;
    __syncthreads();

    for (int i = tid; i < n_e; i += 256) {
        int2 e = epack0[base + i];
        se[i] = e;
        atomicAdd(&hist[e.x >> 17], 1);
    }
    __syncthreads();

    // exclusive scan of hist[128] (Hillis-Steele, full-block barriers)
    if (tid < 128) sc[tid] = hist[tid];
    __syncthreads();
    #pragma unroll
    for (int off = 1; off < 128; off <<= 1) {
        int t = (tid < 128 && tid >= off) ? sc[tid - off] : 0;
        __syncthreads();
        if (tid < 128) sc[tid] += t;
        __syncthreads();
    }
    if (tid < 128) {
        int ex = sc[tid] - hist[tid];
        cur[tid] = ex;
        int row = b * 128 + tid;
        if (row < N_NODES)
            ranges[row] = make_int2(base + ex, base + ex + hist[tid]);
    }
    __syncthreads();

    for (int i = tid; i < n_e; i += 256) {
        int2 e  = se[i];
        int  lr = e.x >> 17;
        int  p  = atomicAdd(&cur[lr], 1);
        epack1[base + p] = make_int2(e.x & 0x1FFFF, e.y);
    }
}

// ---------------------------------------------------------------------------
// Gather SpMM + fused ReLU over bf16 HW rows (256 B each). 16 lanes per node.
__global__ __launch_bounds__(256) void k_spmm_gather(const unsigned short* __restrict__ HWb,
                                                     const int2* __restrict__ ranges,
                                                     const int2* __restrict__ epack,
                                                     float* __restrict__ out) {
    int gid  = blockIdx.x * blockDim.x + threadIdx.x;
    int node = gid >> 4;
    int lane = gid & 15;
    if (node >= N_NODES) return;
    int2 rg = ranges[node];

    float acc[8];
    #pragma unroll
    for (int c = 0; c < 8; ++c) acc[c] = 0.f;

    for (int j = rg.x; j < rg.y; ++j) {
        int2  e = epack[j];
        float v = __int_as_float(e.y);
        uint4 q = ((const uint4*)(HWb + (size_t)e.x * D))[lane];
        acc[0] = fmaf(v, __uint_as_float(q.x << 16),         acc[0]);
        acc[1] = fmaf(v, __uint_as_float(q.x & 0xffff0000u), acc[1]);
        acc[2] = fmaf(v, __uint_as_float(q.y << 16),         acc[2]);
        acc[3] = fmaf(v, __uint_as_float(q.y & 0xffff0000u), acc[3]);
        acc[4] = fmaf(v, __uint_as_float(q.z << 16),         acc[4]);
        acc[5] = fmaf(v, __uint_as_float(q.z & 0xffff0000u), acc[5]);
        acc[6] = fmaf(v, __uint_as_float(q.w << 16),         acc[6]);
        acc[7] = fmaf(v, __uint_as_float(q.w & 0xffff0000u), acc[7]);
    }

    float4 o0 = make_float4(fmaxf(acc[0], 0.f), fmaxf(acc[1], 0.f),
                            fmaxf(acc[2], 0.f), fmaxf(acc[3], 0.f));
    float4 o1 = make_float4(fmaxf(acc[4], 0.f), fmaxf(acc[5], 0.f),
                            fmaxf(acc[6], 0.f), fmaxf(acc[7], 0.f));
    ((float4*)out)[node * 32 + lane * 2]     = o0;
    ((float4*)out)[node * 32 + lane * 2 + 1] = o1;
}

// ---------------------------------------------------------------------------
extern "C" void kernel_launch(void* const* d_in, const int* in_sizes, int n_in,
                              void* d_out, int out_size, void* d_ws, size_t ws_size,
                              hipStream_t stream) {
    const float* H    = (const float*)d_in[0];
    const float* vals = (const float*)d_in[1];
    const float* W    = (const float*)d_in[2];
    const int*   rows = (const int*)d_in[3];
    const int*   cols = (const int*)d_in[4];
    float* out = (float*)d_out;

    char* ws = (char*)d_ws;
    unsigned short* Wb     = (unsigned short*)(ws + WB_OFF);
    unsigned short* HWb    = (unsigned short*)(ws + HWB_OFF);
    int*            bcnt   = (int*)(ws + BCNT_OFF);
    int2*           ranges = (int2*)(ws + RANGES_OFF);
    int2*           epack0 = (int2*)(ws + EPACK0_OFF);
    int2*           epack1 = (int2*)(ws + EPACK1_OFF);

    // dense path: HWb = bf16(H @ W^T), MFMA
    k_cast_w<<<64, 256, 0, stream>>>(W, Wb);
    k_gemm_mfma<<<(N_NODES / 16 + 3) / 4, 256, 0, stream>>>(H, Wb, HWb);

    // CSR build: coarse bucket + per-bucket counting sort
    hipMemsetAsync(bcnt, 0, NB * sizeof(int), stream);
    k_bucket_coarse<<<NBLK_BUCKET, 256, 0, stream>>>(rows, cols, vals, bcnt, epack0);
    k_sort_bucket<<<NB, 256, 0, stream>>>(bcnt, epack0, epack1, ranges);

    // atomic-free gather SpMM + ReLU
    k_spmm_gather<<<(N_NODES * 16 + 255) / 256, 256, 0, stream>>>(HWb, ranges, epack1, out);
}

// Round 6
// 264.429 us; speedup vs baseline: 10.8160x; 1.0663x over previous
//
#include <hip/hip_runtime.h>

#define N_NODES 100000
#define N_EDGES 1600000
#define D 128

#define NB 782                  // coarse buckets: 128 rows each
#define SLOT 2560               // slots per bucket (mean 2046 + 11 sigma slack)
#define CHUNK 6400              // edges per bucket_coarse block
#define NBLK_BUCKET 250         // 250 * 6400 = 1.6M

// workspace layout (bytes)
#define WB_OFF     0u           // 32 KB bf16 W
#define HWB_OFF    65536u       // 25.6 MB bf16 HW
#define BCNT_OFF   25665536u    // 782 ints (pad to 4 KB)
#define EPACK0_OFF 25669632u    // NB*SLOT int2 = 16,015,360 B
// end ~41.7 MB

typedef unsigned int uint;
typedef __attribute__((ext_vector_type(4))) float f32x4;
typedef __attribute__((ext_vector_type(8))) short bf16x8;

__device__ __forceinline__ unsigned short f2bf(float x) {
    uint u = __float_as_uint(x);
    uint r = u + 0x7fffu + ((u >> 16) & 1u);   // round-to-nearest-even
    return (unsigned short)(r >> 16);
}

__device__ __forceinline__ void acc8(float acc[8], uint4 q, float v) {
    acc[0] = fmaf(v, __uint_as_float(q.x << 16),         acc[0]);
    acc[1] = fmaf(v, __uint_as_float(q.x & 0xffff0000u), acc[1]);
    acc[2] = fmaf(v, __uint_as_float(q.y << 16),         acc[2]);
    acc[3] = fmaf(v, __uint_as_float(q.y & 0xffff0000u), acc[3]);
    acc[4] = fmaf(v, __uint_as_float(q.z << 16),         acc[4]);
    acc[5] = fmaf(v, __uint_as_float(q.z & 0xffff0000u), acc[5]);
    acc[6] = fmaf(v, __uint_as_float(q.w << 16),         acc[6]);
    acc[7] = fmaf(v, __uint_as_float(q.w & 0xffff0000u), acc[7]);
}

// ---------------------------------------------------------------------------
__global__ void k_cast_w(const float* __restrict__ W, unsigned short* __restrict__ Wb) {
    int i = blockIdx.x * blockDim.x + threadIdx.x;   // 0..16383
    Wb[i] = f2bf(W[i]);
}

// ---------------------------------------------------------------------------
// HWb = bf16( H @ W^T ) via mfma_f32_16x16x32_bf16. One wave per 16 rows.
__global__ __launch_bounds__(256) void k_gemm_mfma(const float* __restrict__ H,
                                                   const unsigned short* __restrict__ Wb,
                                                   unsigned short* __restrict__ HWb) {
    const int wave = threadIdx.x >> 6;
    const int lane = threadIdx.x & 63;
    const int rowtile = blockIdx.x * 4 + wave;       // 0..6249
    if (rowtile >= N_NODES / 16) return;
    const int rowbase = rowtile * 16;
    const int m    = lane & 15;
    const int quad = lane >> 4;

    f32x4 acc[8];
    #pragma unroll
    for (int nt = 0; nt < 8; ++nt) acc[nt] = (f32x4){0.f, 0.f, 0.f, 0.f};

    const float* hrow = H + (size_t)(rowbase + m) * D;

    #pragma unroll
    for (int ks = 0; ks < 4; ++ks) {
        const int k0 = ks * 32 + quad * 8;
        float4 a0 = *(const float4*)(hrow + k0);
        float4 a1 = *(const float4*)(hrow + k0 + 4);
        bf16x8 afr;
        afr[0] = (short)f2bf(a0.x); afr[1] = (short)f2bf(a0.y);
        afr[2] = (short)f2bf(a0.z); afr[3] = (short)f2bf(a0.w);
        afr[4] = (short)f2bf(a1.x); afr[5] = (short)f2bf(a1.y);
        afr[6] = (short)f2bf(a1.z); afr[7] = (short)f2bf(a1.w);
        #pragma unroll
        for (int nt = 0; nt < 8; ++nt) {
            bf16x8 bfr = *(const bf16x8*)(Wb + (size_t)(nt * 16 + m) * D + k0);
            acc[nt] = __builtin_amdgcn_mfma_f32_16x16x32_bf16(afr, bfr, acc[nt], 0, 0, 0);
        }
    }

    #pragma unroll
    for (int nt = 0; nt < 8; ++nt) {
        #pragma unroll
        for (int r = 0; r < 4; ++r) {
            int orow = rowbase + quad * 4 + r;
            HWb[(size_t)orow * D + nt * 16 + m] = f2bf(acc[nt][r]);
        }
    }
}

// ---------------------------------------------------------------------------
// Pass 1: coarse-bucket edges by row>>7. Block-local LDS count, one global
// atomic span reservation per (block,bucket), dense-in-time placement.
// epack0 entry: x = (local_row<<17) | col, y = val bits.
__global__ __launch_bounds__(256) void k_bucket_coarse(const int* __restrict__ rows,
                                                       const int* __restrict__ cols,
                                                       const float* __restrict__ vals,
                                                       int* __restrict__ bcnt,
                                                       int2* __restrict__ epack0) {
    __shared__ int srows[CHUNK];        // 25.6 KB
    __shared__ int hist[NB];            // 3.1 KB
    __shared__ int cur[NB];             // 3.1 KB
    const int tid = threadIdx.x;
    const int e0  = blockIdx.x * CHUNK;

    for (int b = tid; b < NB; b += 256) hist[b] = 0;
    __syncthreads();

    for (int i = tid; i < CHUNK; i += 256) {
        int r = rows[e0 + i];
        srows[i] = r;
        atomicAdd(&hist[r >> 7], 1);
    }
    __syncthreads();

    for (int b = tid; b < NB; b += 256) {
        int c = hist[b];
        int base = (c > 0) ? atomicAdd(&bcnt[b], c) : 0;
        cur[b] = b * SLOT + base;
    }
    __syncthreads();

    for (int i = tid; i < CHUNK; i += 256) {
        int r = srows[i];
        int b = r >> 7;
        int p = atomicAdd(&cur[b], 1);
        epack0[p] = make_int2(((r & 127) << 17) | cols[e0 + i],
                              __float_as_int(vals[e0 + i]));
    }
}

// ---------------------------------------------------------------------------
// Pass 2 (fused sort + SpMM + ReLU): one block per bucket.
// LDS counting-sort the bucket's edges by local row into scol/sval, then each
// 16-lane group gathers for 8 consecutive rows, unrolled x4 for MLP.
__global__ __launch_bounds__(256) void k_spmm_fused(const int* __restrict__ bcnt,
                                                    const int2* __restrict__ epack0,
                                                    const unsigned short* __restrict__ HWb,
                                                    float* __restrict__ out) {
    __shared__ int   scol[SLOT];        // 10.24 KB
    __shared__ float sval[SLOT];        // 10.24 KB
    __shared__ int hist[128];
    __shared__ int sc[128];
    __shared__ int cur[128];
    __shared__ int rstart[128];
    const int tid  = threadIdx.x;
    const int b    = blockIdx.x;
    const int base = b * SLOT;
    const int n_e  = bcnt[b];

    if (tid < 128) hist[tid] = 0;
    __syncthreads();

    for (int i = tid; i < n_e; i += 256)
        atomicAdd(&hist[epack0[base + i].x >> 17], 1);
    __syncthreads();

    // exclusive scan of hist[128]
    if (tid < 128) sc[tid] = hist[tid];
    __syncthreads();
    #pragma unroll
    for (int off = 1; off < 128; off <<= 1) {
        int t = (tid < 128 && tid >= off) ? sc[tid - off] : 0;
        __syncthreads();
        if (tid < 128) sc[tid] += t;
        __syncthreads();
    }
    if (tid < 128) {
        int ex = sc[tid] - hist[tid];
        rstart[tid] = ex;
        cur[tid] = ex;
    }
    __syncthreads();

    // place sorted (col,val) into LDS (re-read epack0: L2-warm)
    for (int i = tid; i < n_e; i += 256) {
        int2 e  = epack0[base + i];
        int  lr = e.x >> 17;
        int  p  = atomicAdd(&cur[lr], 1);
        scol[p] = e.x & 0x1FFFF;
        sval[p] = __int_as_float(e.y);
    }
    __syncthreads();

    // gather phase: group (tid>>4) handles rows group*8 .. group*8+7
    const int lane  = tid & 15;
    const int group = tid >> 4;

    #pragma unroll
    for (int rr = 0; rr < 8; ++rr) {
        const int lr  = group * 8 + rr;
        const int row = b * 128 + lr;
        if (row >= N_NODES) continue;
        const int s  = rstart[lr];
        const int e_ = cur[lr];                  // == start + count after placement

        float acc[8];
        #pragma unroll
        for (int c = 0; c < 8; ++c) acc[c] = 0.f;

        int j = s;
        for (; j + 3 < e_; j += 4) {
            int   c0 = scol[j],     c1 = scol[j + 1], c2 = scol[j + 2], c3 = scol[j + 3];
            float v0 = sval[j],     v1 = sval[j + 1], v2 = sval[j + 2], v3 = sval[j + 3];
            uint4 q0 = ((const uint4*)(HWb + (size_t)c0 * D))[lane];
            uint4 q1 = ((const uint4*)(HWb + (size_t)c1 * D))[lane];
            uint4 q2 = ((const uint4*)(HWb + (size_t)c2 * D))[lane];
            uint4 q3 = ((const uint4*)(HWb + (size_t)c3 * D))[lane];
            acc8(acc, q0, v0); acc8(acc, q1, v1);
            acc8(acc, q2, v2); acc8(acc, q3, v3);
        }
        for (; j < e_; ++j) {
            int   c = scol[j];
            float v = sval[j];
            uint4 q = ((const uint4*)(HWb + (size_t)c * D))[lane];
            acc8(acc, q, v);
        }

        float4 o0 = make_float4(fmaxf(acc[0], 0.f), fmaxf(acc[1], 0.f),
                                fmaxf(acc[2], 0.f), fmaxf(acc[3], 0.f));
        float4 o1 = make_float4(fmaxf(acc[4], 0.f), fmaxf(acc[5], 0.f),
                                fmaxf(acc[6], 0.f), fmaxf(acc[7], 0.f));
        ((float4*)out)[row * 32 + lane * 2]     = o0;
        ((float4*)out)[row * 32 + lane * 2 + 1] = o1;
    }
}

// ---------------------------------------------------------------------------
extern "C" void kernel_launch(void* const* d_in, const int* in_sizes, int n_in,
                              void* d_out, int out_size, void* d_ws, size_t ws_size,
                              hipStream_t stream) {
    const float* H    = (const float*)d_in[0];
    const float* vals = (const float*)d_in[1];
    const float* W    = (const float*)d_in[2];
    const int*   rows = (const int*)d_in[3];
    const int*   cols = (const int*)d_in[4];
    float* out = (float*)d_out;

    char* ws = (char*)d_ws;
    unsigned short* Wb     = (unsigned short*)(ws + WB_OFF);
    unsigned short* HWb    = (unsigned short*)(ws + HWB_OFF);
    int*            bcnt   = (int*)(ws + BCNT_OFF);
    int2*           epack0 = (int2*)(ws + EPACK0_OFF);

    // dense path: HWb = bf16(H @ W^T), MFMA
    k_cast_w<<<64, 256, 0, stream>>>(W, Wb);
    k_gemm_mfma<<<(N_NODES / 16 + 3) / 4, 256, 0, stream>>>(H, Wb, HWb);

    // coarse bucket, then fused sort+SpMM+ReLU
    hipMemsetAsync(bcnt, 0, NB * sizeof(int), stream);
    k_bucket_coarse<<<NBLK_BUCKET, 256, 0, stream>>>(rows, cols, vals, bcnt, epack0);
    k_spmm_fused<<<NB, 256, 0, stream>>>(bcnt, epack0, HWb, out);
}